// Round 1
// baseline (245.622 us; speedup 1.0000x reference)
//
#include <hip/hip_runtime.h>
#include <hip/hip_fp16.h>

#define NN 4096
#define FIN 20
#define NH 4
#define DH 64
#define ALPHA 0.2f

typedef _Float16 f16x8 __attribute__((ext_vector_type(8)));
typedef float f32x4 __attribute__((ext_vector_type(4)));

// ---- kernel 1: pack adjacency (int 0/1) into bitmask, bits[n][128] words ----
__global__ void k_pack(const int* __restrict__ adj, unsigned int* __restrict__ bits) {
    int t = blockIdx.x * blockDim.x + threadIdx.x;   // element index
    int pred = adj[t] > 0;
    unsigned long long m = __ballot(pred);
    if ((threadIdx.x & 63) == 0) {
        int w = t >> 5;
        bits[w]     = (unsigned int)(m & 0xffffffffull);
        bits[w + 1] = (unsigned int)(m >> 32);
    }
}

// ---- kernel 2: layer0 Wh -> whT (f16, [h][d][n]) + fs/fd ([h][n]) ----
__global__ __launch_bounds__(256) void k_l0wh(const float* __restrict__ x,
        const float* __restrict__ W0, const float* __restrict__ a0,
        _Float16* __restrict__ whT, float* __restrict__ fs, float* __restrict__ fd) {
    __shared__ float xs[64 * FIN];
    int n0 = blockIdx.x * 64;
    int tid = threadIdx.x;
    for (int i = tid; i < 64 * FIN; i += 256) xs[i] = x[n0 * FIN + i];
    __syncthreads();
    int h = tid >> 6, d = tid & 63;
    float w0r[FIN];
#pragma unroll
    for (int f = 0; f < FIN; ++f) w0r[f] = W0[(h * FIN + f) * DH + d];
    float asrc = a0[h * 2 * DH + d];
    float adst = a0[h * 2 * DH + DH + d];
    f16x8 wv[8];
#pragma unroll
    for (int n = 0; n < 64; ++n) {
        float wh = 0.f;
#pragma unroll
        for (int f = 0; f < FIN; ++f) wh = fmaf(xs[n * FIN + f], w0r[f], wh);
        wv[n >> 3][n & 7] = (_Float16)wh;
        float sv = wh * asrc, dv = wh * adst;
#pragma unroll
        for (int off = 32; off >= 1; off >>= 1) {
            sv += __shfl_xor(sv, off);
            dv += __shfl_xor(dv, off);
        }
        if (d == 0) { fs[h * NN + n0 + n] = sv; fd[h * NN + n0 + n] = dv; }
    }
    _Float16* dst = whT + ((size_t)(h * DH + d) * NN + n0);
#pragma unroll
    for (int i = 0; i < 8; ++i) *(f16x8*)(dst + 8 * i) = wv[i];
}

// ---- kernel 3: fdmax per head ----
__global__ void k_fdmax(const float* __restrict__ fd, float* __restrict__ fdmax) {
    __shared__ float red[256];
    int h = blockIdx.x, tid = threadIdx.x;
    float m = -1e30f;
    for (int i = tid; i < NN; i += 256) m = fmaxf(m, fd[h * NN + i]);
    red[tid] = m; __syncthreads();
    for (int s = 128; s > 0; s >>= 1) {
        if (tid < s) red[tid] = fmaxf(red[tid], red[tid + s]);
        __syncthreads();
    }
    if (tid == 0) fdmax[h] = red[0];
}

// ---- attention: fused mask+softmax(single pass, upper-bound max)+PV+ELU ----
// MODE 0: write h16 [n][H*DH] f16   MODE 1: write out1 [h][n][DH] f32
template<int MODE>
__global__ __launch_bounds__(64) void k_attn(const float* __restrict__ fs,
        const float* __restrict__ fd, const float* __restrict__ fdmax,
        const _Float16* __restrict__ whT, const unsigned int* __restrict__ bits,
        void* __restrict__ outp) {
    int h = blockIdx.x >> 8;
    int row0 = (blockIdx.x & 255) << 4;
    int l = threadIdx.x;
    int rl = l & 15, g = l >> 4;
    int row = row0 + rl;
    float fsr = fs[h * NN + row];
    float s0 = fsr + fdmax[h];
    float mrow = fmaxf(s0, ALPHA * s0);          // upper bound of row max of lrelu
    const float* fdp = fd + h * NN;
    const unsigned char* bitrow = ((const unsigned char*)bits) + (size_t)row * (NN / 8);
    const _Float16* whb = whT + (size_t)h * DH * NN;
    f32x4 acc0 = {0,0,0,0}, acc1 = {0,0,0,0}, acc2 = {0,0,0,0}, acc3 = {0,0,0,0};
    float lsum = 0.f;
    for (int j0 = 0; j0 < NN; j0 += 32) {
        int jb = j0 + 8 * g;
        float4 fda = *(const float4*)(fdp + jb);
        float4 fdb = *(const float4*)(fdp + jb + 4);
        unsigned int mb = bitrow[jb >> 3];
        float fv[8] = {fda.x, fda.y, fda.z, fda.w, fdb.x, fdb.y, fdb.z, fdb.w};
        f16x8 av;
#pragma unroll
        for (int i = 0; i < 8; ++i) {
            float s = fsr + fv[i];
            float e = fmaxf(s, ALPHA * s);       // leaky relu
            float t = e - mrow;                  // <= 0
            t = ((mb >> i) & 1u) ? t : -1e30f;   // mask -> exp gives 0
            float p = __expf(t);
            lsum += p;
            av[i] = (_Float16)p;
        }
        const _Float16* bbase = whb + jb;
#pragma unroll
        for (int t4 = 0; t4 < 4; ++t4) {
            f16x8 bv = *(const f16x8*)(bbase + (size_t)(16 * t4 + rl) * NN);
            if (t4 == 0) acc0 = __builtin_amdgcn_mfma_f32_16x16x32_f16(av, bv, acc0, 0, 0, 0);
            if (t4 == 1) acc1 = __builtin_amdgcn_mfma_f32_16x16x32_f16(av, bv, acc1, 0, 0, 0);
            if (t4 == 2) acc2 = __builtin_amdgcn_mfma_f32_16x16x32_f16(av, bv, acc2, 0, 0, 0);
            if (t4 == 3) acc3 = __builtin_amdgcn_mfma_f32_16x16x32_f16(av, bv, acc3, 0, 0, 0);
        }
    }
    lsum += __shfl_xor(lsum, 16);
    lsum += __shfl_xor(lsum, 32);                // all lanes: L for row (lane&15)
    float Lr[4];
#pragma unroll
    for (int i = 0; i < 4; ++i) Lr[i] = __shfl(lsum, 4 * g + i);
    f32x4 accs[4] = {acc0, acc1, acc2, acc3};
#pragma unroll
    for (int t4 = 0; t4 < 4; ++t4) {
#pragma unroll
        for (int i = 0; i < 4; ++i) {
            float v = accs[t4][i] / Lr[i];
            float o = v > 0.f ? v : __expf(v) - 1.f;   // ELU
            int r = row0 + 4 * g + i;
            int d = 16 * t4 + rl;
            if (MODE == 0) ((_Float16*)outp)[(size_t)r * (NH * DH) + h * DH + d] = (_Float16)o;
            else           ((float*)outp)[((size_t)h * NN + r) * DH + d] = o;
        }
    }
}

// ---- W1 [h][256][64] f32 -> w1T [h][64][256] f16 ----
__global__ void k_w1t(const float* __restrict__ W1, _Float16* __restrict__ w1T) {
    int tid = threadIdx.x;
    int h = tid >> 6, d = tid & 63;
    for (int f = 0; f < NH * DH; ++f)
        w1T[(size_t)(h * DH + d) * (NH * DH) + f] = (_Float16)W1[(size_t)(h * NH * DH + f) * DH + d];
}

// ---- layer1 Wh via MFMA: h16[4096][256] x W1 -> whT1 + fs/fd ----
__global__ __launch_bounds__(64) void k_l1wh(const _Float16* __restrict__ h16,
        const _Float16* __restrict__ w1T, const float* __restrict__ a1,
        _Float16* __restrict__ whT, float* __restrict__ fs, float* __restrict__ fd) {
    __shared__ _Float16 lt[16][64];
    int h = blockIdx.x >> 8;
    int row0 = (blockIdx.x & 255) << 4;
    int l = threadIdx.x, rl = l & 15, g = l >> 4;
    f32x4 acc0 = {0,0,0,0}, acc1 = {0,0,0,0}, acc2 = {0,0,0,0}, acc3 = {0,0,0,0};
    const _Float16* ap = h16 + (size_t)(row0 + rl) * 256;
    const _Float16* bp = w1T + (size_t)h * DH * 256;
#pragma unroll
    for (int f0 = 0; f0 < 256; f0 += 32) {
        int fb = f0 + 8 * g;
        f16x8 av = *(const f16x8*)(ap + fb);
        f16x8 b0 = *(const f16x8*)(bp + (size_t)(0  + rl) * 256 + fb);
        f16x8 b1 = *(const f16x8*)(bp + (size_t)(16 + rl) * 256 + fb);
        f16x8 b2 = *(const f16x8*)(bp + (size_t)(32 + rl) * 256 + fb);
        f16x8 b3 = *(const f16x8*)(bp + (size_t)(48 + rl) * 256 + fb);
        acc0 = __builtin_amdgcn_mfma_f32_16x16x32_f16(av, b0, acc0, 0, 0, 0);
        acc1 = __builtin_amdgcn_mfma_f32_16x16x32_f16(av, b1, acc1, 0, 0, 0);
        acc2 = __builtin_amdgcn_mfma_f32_16x16x32_f16(av, b2, acc2, 0, 0, 0);
        acc3 = __builtin_amdgcn_mfma_f32_16x16x32_f16(av, b3, acc3, 0, 0, 0);
    }
    f32x4 accs[4] = {acc0, acc1, acc2, acc3};
    float asr[4], adr[4];
#pragma unroll
    for (int t4 = 0; t4 < 4; ++t4) {
        asr[t4] = a1[h * 2 * DH + 16 * t4 + rl];
        adr[t4] = a1[h * 2 * DH + DH + 16 * t4 + rl];
    }
#pragma unroll
    for (int i = 0; i < 4; ++i) {
        float sv = 0.f, dv = 0.f;
#pragma unroll
        for (int t4 = 0; t4 < 4; ++t4) {
            sv = fmaf(accs[t4][i], asr[t4], sv);
            dv = fmaf(accs[t4][i], adr[t4], dv);
        }
#pragma unroll
        for (int off = 1; off <= 8; off <<= 1) {
            sv += __shfl_xor(sv, off);
            dv += __shfl_xor(dv, off);
        }
        if (rl == 0) {
            fs[h * NN + row0 + 4 * g + i] = sv;
            fd[h * NN + row0 + 4 * g + i] = dv;
        }
    }
#pragma unroll
    for (int t4 = 0; t4 < 4; ++t4)
#pragma unroll
        for (int i = 0; i < 4; ++i)
            lt[4 * g + i][16 * t4 + rl] = (_Float16)accs[t4][i];
    __syncthreads();
    f16x8 v0, v1;
#pragma unroll
    for (int n = 0; n < 8; ++n) { v0[n] = lt[n][l]; v1[n] = lt[n + 8][l]; }
    _Float16* dst = whT + (size_t)(h * DH + l) * NN + row0;
    *(f16x8*)(dst) = v0;
    *(f16x8*)(dst + 8) = v1;
}

// ---- combine heads: mean over h of out1 ----
__global__ void k_comb(const float* __restrict__ out1, float* __restrict__ out) {
    int t = blockIdx.x * 256 + threadIdx.x;
    const int S = NN * DH;
    out[t] = 0.25f * (out1[t] + out1[t + S] + out1[t + 2 * S] + out1[t + 3 * S]);
}

extern "C" void kernel_launch(void* const* d_in, const int* in_sizes, int n_in,
                              void* d_out, int out_size, void* d_ws, size_t ws_size,
                              hipStream_t stream) {
    const float* x  = (const float*)d_in[0];
    const int* adj  = (const int*)d_in[1];
    const float* W0 = (const float*)d_in[2];
    const float* a0 = (const float*)d_in[3];
    const float* W1 = (const float*)d_in[4];
    const float* a1 = (const float*)d_in[5];
    float* out = (float*)d_out;
    char* ws = (char*)d_ws;

    unsigned int* bits = (unsigned int*)(ws);                     // 2MB
    _Float16* whT0 = (_Float16*)(ws + (2ull << 20));              // 2MB
    _Float16* h16  = (_Float16*)(ws + (4ull << 20));              // 2MB
    _Float16* w1T  = (_Float16*)(ws + (6ull << 20));              // 128KB
    _Float16* whT1 = (_Float16*)(ws + (6ull << 20) + (256ull << 10)); // 2MB
    float* fs0  = (float*)(ws + (9ull << 20));
    float* fd0  = fs0 + NH * NN;
    float* fs1  = fd0 + NH * NN;
    float* fd1  = fs1 + NH * NN;
    float* fdm0 = fd1 + NH * NN;
    float* fdm1 = fdm0 + 8;
    float* out1 = (float*)(ws + (10ull << 20));                   // 4MB

    k_pack<<<(NN * (NN / 256)), 256, 0, stream>>>(adj, bits);
    k_w1t<<<1, 256, 0, stream>>>(W1, w1T);
    k_l0wh<<<NN / 64, 256, 0, stream>>>(x, W0, a0, whT0, fs0, fd0);
    k_fdmax<<<NH, 256, 0, stream>>>(fd0, fdm0);
    k_attn<0><<<NH * (NN / 16), 64, 0, stream>>>(fs0, fd0, fdm0, whT0, bits, h16);
    k_l1wh<<<NH * (NN / 16), 64, 0, stream>>>(h16, w1T, a1, whT1, fs1, fd1);
    k_fdmax<<<NH, 256, 0, stream>>>(fd1, fdm1);
    k_attn<1><<<NH * (NN / 16), 64, 0, stream>>>(fs1, fd1, fdm1, whT1, bits, out1);
    k_comb<<<(NN * DH) / 256, 256, 0, stream>>>(out1, out);
}

// Round 2
// 158.001 us; speedup vs baseline: 1.5546x; 1.5546x over previous
//
#include <hip/hip_runtime.h>
#include <hip/hip_fp16.h>

#define NN 4096
#define FIN 20
#define NH 4
#define DH 64
#define ALPHA 0.2f

typedef _Float16 f16x8 __attribute__((ext_vector_type(8)));
typedef _Float16 f16x4 __attribute__((ext_vector_type(4)));
typedef float f32x4 __attribute__((ext_vector_type(4)));

__device__ inline void atomicMaxF(float* a, float v) {
    if (v >= 0.f) atomicMax((int*)a, __float_as_int(v));
    else atomicMin((unsigned int*)a, __float_as_uint(v));
}

// ---- pack adjacency into bitmask + init fdm ----
__global__ void k_pack(const int* __restrict__ adj, unsigned int* __restrict__ bits,
                       float* __restrict__ fdm) {
    int t = blockIdx.x * blockDim.x + threadIdx.x;
    if (blockIdx.x == 0 && threadIdx.x < 16) fdm[threadIdx.x] = -3e38f;
    int pred = adj[t] > 0;
    unsigned long long m = __ballot(pred);
    if ((threadIdx.x & 63) == 0) {
        int w = t >> 5;
        bits[w]     = (unsigned int)m;
        bits[w + 1] = (unsigned int)(m >> 32);
    }
}

// ---- layer0 Wh -> whT (f16, [h][d][n]); 16 nodes per block ----
__global__ __launch_bounds__(256) void k_l0wh(const float* __restrict__ x,
        const float* __restrict__ W0, _Float16* __restrict__ whT) {
    __shared__ float xs[16 * FIN];
    int n0 = blockIdx.x * 16;
    int tid = threadIdx.x;
    for (int i = tid; i < 16 * FIN; i += 256) xs[i] = x[n0 * FIN + i];
    __syncthreads();
    int h = tid >> 6, d = tid & 63;
    float w0r[FIN];
#pragma unroll
    for (int f = 0; f < FIN; ++f) w0r[f] = W0[(h * FIN + f) * DH + d];
    f16x8 wv[2];
#pragma unroll
    for (int n = 0; n < 16; ++n) {
        float wh = 0.f;
#pragma unroll
        for (int f = 0; f < FIN; ++f) wh = fmaf(xs[n * FIN + f], w0r[f], wh);
        wv[n >> 3][n & 7] = (_Float16)wh;
    }
    _Float16* dst = whT + ((size_t)(h * DH + d) * NN + n0);
    *(f16x8*)(dst) = wv[0];
    *(f16x8*)(dst + 8) = wv[1];
}

// ---- fs/fd from whT (coalesced) + fused per-head fdmax via atomics ----
__global__ __launch_bounds__(256) void k_fsd(const _Float16* __restrict__ whT,
        const float* __restrict__ a, float* __restrict__ fs, float* __restrict__ fd,
        float* __restrict__ fdm) {
    int u = blockIdx.x * 256 + threadIdx.x;     // h*NN + n
    int h = u >> 12;
    const _Float16* p = whT + (size_t)h * DH * NN + (u & (NN - 1));
    const float* av = a + h * 2 * DH;
    float s = 0.f, dv = 0.f;
#pragma unroll 8
    for (int d = 0; d < DH; ++d) {
        float wv = (float)p[(size_t)d * NN];
        s  = fmaf(wv, av[d], s);
        dv = fmaf(wv, av[DH + d], dv);
    }
    fs[u] = s; fd[u] = dv;
    float m = dv;
#pragma unroll
    for (int off = 1; off <= 32; off <<= 1) m = fmaxf(m, __shfl_xor(m, off));
    __shared__ float mx[4];
    if ((threadIdx.x & 63) == 0) mx[threadIdx.x >> 6] = m;
    __syncthreads();
    if (threadIdx.x == 0) {
        m = fmaxf(fmaxf(mx[0], mx[1]), fmaxf(mx[2], mx[3]));
        atomicMaxF(fdm + h, m);
    }
}

// ---- W1 [h][256][64] -> w1T [h][64][256] f16 (read-coalesced) ----
__global__ void k_w1t(const float* __restrict__ W1, _Float16* __restrict__ w1T) {
    int u = blockIdx.x * 256 + threadIdx.x;     // 0..65535
    int h = u >> 14, f = (u >> 6) & 255, d = u & 63;
    w1T[((size_t)(h * DH + d) << 8) + f] = (_Float16)W1[u];
}

// ---- attention: 8 waves, col-split, 2 row-tiles/wave, LDS reduce ----
// MODE 0: write h16 [n][H*DH] f16   MODE 1: write out1 [h][n][DH] f32
template<int MODE>
__global__ __launch_bounds__(512, 4) void k_attn(const float* __restrict__ fs,
        const float* __restrict__ fd, const float* __restrict__ fdmax,
        const _Float16* __restrict__ whT, const unsigned int* __restrict__ bits,
        void* __restrict__ outp) {
    __shared__ float red[8][16][64];
    __shared__ float lred[8][16];
    int h = blockIdx.x >> 7;
    int row0 = (blockIdx.x & 127) << 5;         // 32 rows per block
    int tid = threadIdx.x;
    int l = tid & 63, w = tid >> 6;
    int rl = l & 15, g = l >> 4;
    int r0 = row0 + rl, r1 = row0 + 16 + rl;
    float fsr0 = fs[h * NN + r0], fsr1 = fs[h * NN + r1];
    float fm = fdmax[h];
    float s0u = fsr0 + fm, s1u = fsr1 + fm;
    float m0 = fmaxf(s0u, ALPHA * s0u);         // upper bound of row max
    float m1 = fmaxf(s1u, ALPHA * s1u);
    const float* fdp = fd + h * NN;
    const unsigned char* br0 = (const unsigned char*)bits + (size_t)r0 * (NN / 8);
    const unsigned char* br1 = (const unsigned char*)bits + (size_t)r1 * (NN / 8);
    const _Float16* whb = whT + (size_t)h * DH * NN;
    f32x4 a0[4] = {{0,0,0,0},{0,0,0,0},{0,0,0,0},{0,0,0,0}};
    f32x4 a1[4] = {{0,0,0,0},{0,0,0,0},{0,0,0,0},{0,0,0,0}};
    f32x4 al0 = {0,0,0,0}, al1 = {0,0,0,0};
    f16x8 ones;
#pragma unroll
    for (int i = 0; i < 8; ++i) ones[i] = (_Float16)1.0f;
    int c0 = w << 9;                            // 512 cols per wave
    for (int j0 = c0; j0 < c0 + 512; j0 += 32) {
        int jb = j0 + 8 * g;
        float4 fa = *(const float4*)(fdp + jb);
        float4 fb = *(const float4*)(fdp + jb + 4);
        unsigned int mb0 = br0[jb >> 3], mb1 = br1[jb >> 3];
        float fv[8] = {fa.x, fa.y, fa.z, fa.w, fb.x, fb.y, fb.z, fb.w};
        f16x8 av0, av1;
#pragma unroll
        for (int i = 0; i < 8; ++i) {
            float s0 = fsr0 + fv[i];
            float e0 = fmaxf(s0, ALPHA * s0) - m0;
            e0 = ((mb0 >> i) & 1u) ? e0 : -1e30f;
            av0[i] = (_Float16)__expf(e0);
            float s1 = fsr1 + fv[i];
            float e1 = fmaxf(s1, ALPHA * s1) - m1;
            e1 = ((mb1 >> i) & 1u) ? e1 : -1e30f;
            av1[i] = (_Float16)__expf(e1);
        }
        al0 = __builtin_amdgcn_mfma_f32_16x16x32_f16(av0, ones, al0, 0, 0, 0);
        al1 = __builtin_amdgcn_mfma_f32_16x16x32_f16(av1, ones, al1, 0, 0, 0);
        const _Float16* bb = whb + jb;
#pragma unroll
        for (int t4 = 0; t4 < 4; ++t4) {
            f16x8 bv = *(const f16x8*)(bb + (size_t)(16 * t4 + rl) * NN);
            a0[t4] = __builtin_amdgcn_mfma_f32_16x16x32_f16(av0, bv, a0[t4], 0, 0, 0);
            a1[t4] = __builtin_amdgcn_mfma_f32_16x16x32_f16(av1, bv, a1[t4], 0, 0, 0);
        }
    }
    // ---- pass rt=0: stage, reduce, epilogue ----
#pragma unroll
    for (int t4 = 0; t4 < 4; ++t4)
#pragma unroll
        for (int i = 0; i < 4; ++i) red[w][t4 * 4 + i][l] = a0[t4][i];
    if (rl == 0) {
#pragma unroll
        for (int i = 0; i < 4; ++i) lred[w][4 * g + i] = al0[i];
    }
    __syncthreads();
    if (w < 4) {
#pragma unroll
        for (int i = 0; i < 4; ++i) {
            float v = 0.f, L = 0.f;
#pragma unroll
            for (int cc = 0; cc < 8; ++cc) { v += red[cc][w * 4 + i][l]; L += lred[cc][4 * g + i]; }
            float o = v / L;
            o = o > 0.f ? o : __expf(o) - 1.f;   // ELU
            int r = row0 + 4 * g + i;
            int d = 16 * w + rl;
            if (MODE == 0) ((_Float16*)outp)[(size_t)r * (NH * DH) + h * DH + d] = (_Float16)o;
            else           ((float*)outp)[((size_t)h * NN + r) * DH + d] = o;
        }
    }
    __syncthreads();
    // ---- pass rt=1 ----
#pragma unroll
    for (int t4 = 0; t4 < 4; ++t4)
#pragma unroll
        for (int i = 0; i < 4; ++i) red[w][t4 * 4 + i][l] = a1[t4][i];
    if (rl == 0) {
#pragma unroll
        for (int i = 0; i < 4; ++i) lred[w][4 * g + i] = al1[i];
    }
    __syncthreads();
    if (w < 4) {
#pragma unroll
        for (int i = 0; i < 4; ++i) {
            float v = 0.f, L = 0.f;
#pragma unroll
            for (int cc = 0; cc < 8; ++cc) { v += red[cc][w * 4 + i][l]; L += lred[cc][4 * g + i]; }
            float o = v / L;
            o = o > 0.f ? o : __expf(o) - 1.f;
            int r = row0 + 16 + 4 * g + i;
            int d = 16 * w + rl;
            if (MODE == 0) ((_Float16*)outp)[(size_t)r * (NH * DH) + h * DH + d] = (_Float16)o;
            else           ((float*)outp)[((size_t)h * NN + r) * DH + d] = o;
        }
    }
}

// ---- layer1 Wh via MFMA, 4 waves split K, LDS reduce; writes whT1 ----
__global__ __launch_bounds__(256) void k_l1wh(const _Float16* __restrict__ h16,
        const _Float16* __restrict__ w1T, _Float16* __restrict__ whT) {
    __shared__ float red[4][16][64];
    __shared__ _Float16 lt[16][64];
    int h = blockIdx.x >> 8;
    int row0 = (blockIdx.x & 255) << 4;
    int tid = threadIdx.x;
    int l = tid & 63, w = tid >> 6;
    int rl = l & 15, g = l >> 4;
    f32x4 acc[4] = {{0,0,0,0},{0,0,0,0},{0,0,0,0},{0,0,0,0}};
    const _Float16* ap = h16 + (size_t)(row0 + rl) * (NH * DH) + w * 64;
    const _Float16* bp = w1T + ((size_t)h * DH << 8) + w * 64;
#pragma unroll
    for (int j = 0; j < 2; ++j) {
        int fb = j * 32 + 8 * g;
        f16x8 avv = *(const f16x8*)(ap + fb);
#pragma unroll
        for (int t4 = 0; t4 < 4; ++t4) {
            f16x8 bv = *(const f16x8*)(bp + ((size_t)(16 * t4 + rl) << 8) + fb);
            acc[t4] = __builtin_amdgcn_mfma_f32_16x16x32_f16(avv, bv, acc[t4], 0, 0, 0);
        }
    }
#pragma unroll
    for (int t4 = 0; t4 < 4; ++t4)
#pragma unroll
        for (int i = 0; i < 4; ++i) red[w][t4 * 4 + i][l] = acc[t4][i];
    __syncthreads();
    // epilogue: wave w takes t4=w; lane has rows 4g+i, d = 16w+rl
#pragma unroll
    for (int i = 0; i < 4; ++i) {
        float v = red[0][w * 4 + i][l] + red[1][w * 4 + i][l]
                + red[2][w * 4 + i][l] + red[3][w * 4 + i][l];
        lt[4 * g + i][16 * w + rl] = (_Float16)v;
    }
    __syncthreads();
    int d = tid & 63, rb = tid >> 6;
    f16x4 o;
#pragma unroll
    for (int j = 0; j < 4; ++j) o[j] = lt[rb * 4 + j][d];
    *(f16x4*)(whT + (size_t)(h * DH + d) * NN + row0 + rb * 4) = o;
}

// ---- combine heads: mean over h ----
__global__ void k_comb(const float* __restrict__ out1, float* __restrict__ out) {
    int t = blockIdx.x * 256 + threadIdx.x;
    const int S = NN * DH;
    out[t] = 0.25f * (out1[t] + out1[t + S] + out1[t + 2 * S] + out1[t + 3 * S]);
}

extern "C" void kernel_launch(void* const* d_in, const int* in_sizes, int n_in,
                              void* d_out, int out_size, void* d_ws, size_t ws_size,
                              hipStream_t stream) {
    const float* x  = (const float*)d_in[0];
    const int* adj  = (const int*)d_in[1];
    const float* W0 = (const float*)d_in[2];
    const float* a0 = (const float*)d_in[3];
    const float* W1 = (const float*)d_in[4];
    const float* a1 = (const float*)d_in[5];
    float* out = (float*)d_out;
    char* ws = (char*)d_ws;

    unsigned int* bits = (unsigned int*)(ws);                          // 2MB
    _Float16* whT0 = (_Float16*)(ws + (2ull << 20));                   // 2MB
    _Float16* h16  = (_Float16*)(ws + (4ull << 20));                   // 2MB
    _Float16* w1T  = (_Float16*)(ws + (6ull << 20));                   // 128KB
    _Float16* whT1 = (_Float16*)(ws + (6ull << 20) + (256ull << 10));  // 2MB
    float* fs0  = (float*)(ws + (9ull << 20));
    float* fd0  = fs0 + NH * NN;
    float* fs1  = fd0 + NH * NN;
    float* fd1  = fs1 + NH * NN;
    float* fdm0 = fd1 + NH * NN;   // 8 floats
    float* fdm1 = fdm0 + 8;
    float* out1 = (float*)(ws + (10ull << 20));                        // 4MB

    k_pack<<<(NN / 256) * NN, 256, 0, stream>>>(adj, bits, fdm0);
    k_w1t<<<(NH * NH * DH * DH) / 256, 256, 0, stream>>>(W1, w1T);
    k_l0wh<<<NN / 16, 256, 0, stream>>>(x, W0, whT0);
    k_fsd<<<NH * NN / 256, 256, 0, stream>>>(whT0, a0, fs0, fd0, fdm0);
    k_attn<0><<<NH * (NN / 32), 512, 0, stream>>>(fs0, fd0, fdm0, whT0, bits, h16);
    k_l1wh<<<NH * (NN / 16), 256, 0, stream>>>(h16, w1T, whT1);
    k_fsd<<<NH * NN / 256, 256, 0, stream>>>(whT1, a1, fs1, fd1, fdm1);
    k_attn<1><<<NH * (NN / 32), 512, 0, stream>>>(fs1, fd1, fdm1, whT1, bits, out1);
    k_comb<<<(NN * DH) / 256, 256, 0, stream>>>(out1, out);
}